// Round 2
// baseline (184.369 us; speedup 1.0000x reference)
//
#include <hip/hip_runtime.h>

#define BATCH 4096
#define SEQ   128
#define DIN   64
#define DOUT  128
#define HID   32
#define WPB   4   // waves (= batches) per block

// One wave per batch, 4 waves per 256-thread block. No __syncthreads needed:
// each wave uses only its own LDS slice, and per-wave DS ops are in-order.
__global__ __launch_bounds__(WPB * 64) void fused_mlp_topk_kernel(
    const float* __restrict__ x,      // (B, S, DIN)
    const float* __restrict__ Wn,     // (DIN, DOUT)
    const float* __restrict__ bn,     // (DOUT)
    const float* __restrict__ W1,     // (DOUT, HID)
    const float* __restrict__ b1,     // (HID)
    const float* __restrict__ W2,     // (HID, 4)
    const float* __restrict__ b2,     // (4)
    const int*   __restrict__ mask,   // (B, S) int32 0/1
    float*       __restrict__ out)    // (B, 2, 4)
{
    const int tid  = threadIdx.x;
    const int lane = tid & 63;
    const int w    = tid >> 6;
    const int b    = blockIdx.x * WPB + w;

    __shared__ __align__(16) float xs[WPB][2][DIN];    // gathered x rows
    __shared__ __align__(16) float fs[WPB][2][DOUT];   // layer-0 output
    __shared__ __align__(16) float hs[WPB][2][HID];    // layer-1 output

    // ---- first two valid (mask=True) positions, stable order ----
    const int m0 = mask[b * SEQ + lane];
    const int m1 = mask[b * SEQ + 64 + lane];
    const unsigned long long bal0 = __ballot(m0 != 0);
    const unsigned long long bal1 = __ballot(m1 != 0);

    int i0 = 0, i1 = 0, cnt = 0;
    if (bal0) {
        i0 = __builtin_ctzll(bal0);
        unsigned long long rem = bal0 & (bal0 - 1ull);
        if (rem)       { i1 = __builtin_ctzll(rem);       cnt = 2; }
        else if (bal1) { i1 = 64 + __builtin_ctzll(bal1); cnt = 2; }
        else           { i1 = i0;                         cnt = 1; }
    } else if (bal1) {
        i0 = 64 + __builtin_ctzll(bal1);
        unsigned long long rem = bal1 & (bal1 - 1ull);
        if (rem) { i1 = 64 + __builtin_ctzll(rem); cnt = 2; }
        else     { i1 = i0;                        cnt = 1; }
    }
    // cnt==1: i1=i0 so preds1==preds0 == the nv==1 "where" branch.

    // ---- stage the two selected x rows in wave-private LDS ----
    const size_t xbase = (size_t)b * SEQ * DIN;
    xs[w][0][lane] = x[xbase + (size_t)i0 * DIN + lane];
    xs[w][1][lane] = x[xbase + (size_t)i1 * DIN + lane];

    // ---- layer 0: feats = x_row @ Wn + bn; lane owns cols {2*lane, 2*lane+1}
    const int j0 = lane * 2;
    float f00 = bn[j0], f01 = bn[j0 + 1];   // row 0
    float f10 = f00,    f11 = f01;          // row 1
    #pragma unroll
    for (int d = 0; d < DIN; d += 4) {
        const float4 xa = *(const float4*)&xs[w][0][d];  // broadcast reads
        const float4 xb = *(const float4*)&xs[w][1][d];
        const float2 wa = *(const float2*)&Wn[(d + 0) * DOUT + j0];
        const float2 wb = *(const float2*)&Wn[(d + 1) * DOUT + j0];
        const float2 wc = *(const float2*)&Wn[(d + 2) * DOUT + j0];
        const float2 wd = *(const float2*)&Wn[(d + 3) * DOUT + j0];
        f00 = fmaf(xa.x, wa.x, f00);  f01 = fmaf(xa.x, wa.y, f01);
        f10 = fmaf(xb.x, wa.x, f10);  f11 = fmaf(xb.x, wa.y, f11);
        f00 = fmaf(xa.y, wb.x, f00);  f01 = fmaf(xa.y, wb.y, f01);
        f10 = fmaf(xb.y, wb.x, f10);  f11 = fmaf(xb.y, wb.y, f11);
        f00 = fmaf(xa.z, wc.x, f00);  f01 = fmaf(xa.z, wc.y, f01);
        f10 = fmaf(xb.z, wc.x, f10);  f11 = fmaf(xb.z, wc.y, f11);
        f00 = fmaf(xa.w, wd.x, f00);  f01 = fmaf(xa.w, wd.y, f01);
        f10 = fmaf(xb.w, wd.x, f10);  f11 = fmaf(xb.w, wd.y, f11);
    }
    *(float2*)&fs[w][0][j0] = make_float2(f00, f01);
    *(float2*)&fs[w][1][j0] = make_float2(f10, f11);

    // ---- layer 1: h = relu(feats @ W1 + b1); lanes 0-31 row0, 32-63 row1 ----
    const int r = lane >> 5;
    const int k = lane & 31;
    float h0 = b1[k], h1 = 0.f, h2 = 0.f, h3 = 0.f;   // 4 indep chains
    #pragma unroll
    for (int j = 0; j < DOUT; j += 4) {
        const float4 fv = *(const float4*)&fs[w][r][j];  // broadcast reads
        h0 = fmaf(fv.x, W1[(j + 0) * HID + k], h0);
        h1 = fmaf(fv.y, W1[(j + 1) * HID + k], h1);
        h2 = fmaf(fv.z, W1[(j + 2) * HID + k], h2);
        h3 = fmaf(fv.w, W1[(j + 3) * HID + k], h3);
    }
    hs[w][r][k] = fmaxf((h0 + h1) + (h2 + h3), 0.0f);

    // ---- layer 2 + selection: lanes 0..7 -> out[b][rr][o] ----
    if (lane < 8) {
        const int rr = lane >> 2;
        const int o  = lane & 3;
        float p0 = b2[o], p1 = 0.f;
        #pragma unroll
        for (int kk = 0; kk < HID; kk += 2) {
            p0 = fmaf(hs[w][rr][kk + 0], W2[(kk + 0) * 4 + o], p0);
            p1 = fmaf(hs[w][rr][kk + 1], W2[(kk + 1) * 4 + o], p1);
        }
        out[b * 8 + lane] = (cnt >= 1) ? (p0 + p1) : 0.0f;
    }
}

extern "C" void kernel_launch(void* const* d_in, const int* in_sizes, int n_in,
                              void* d_out, int out_size, void* d_ws, size_t ws_size,
                              hipStream_t stream) {
    const float* x    = (const float*)d_in[0];
    const float* Wn   = (const float*)d_in[1];
    const float* bn   = (const float*)d_in[2];
    const float* W1   = (const float*)d_in[3];
    const float* b1   = (const float*)d_in[4];
    const float* W2   = (const float*)d_in[5];
    const float* b2   = (const float*)d_in[6];
    const int*   mask = (const int*)d_in[7];
    float* out = (float*)d_out;

    fused_mlp_topk_kernel<<<BATCH / WPB, WPB * 64, 0, stream>>>(
        x, Wn, bn, W1, b1, W2, b2, mask, out);
}